// Round 4
// baseline (299.837 us; speedup 1.0000x reference)
//
#include <hip/hip_runtime.h>

typedef __bf16 bf16;
typedef bf16 v8bf __attribute__((ext_vector_type(8)));
typedef bf16 v4bf __attribute__((ext_vector_type(4)));
typedef float v4f __attribute__((ext_vector_type(4)));
typedef float v16f __attribute__((ext_vector_type(16)));
typedef unsigned int u32;
typedef u32 v4u __attribute__((ext_vector_type(4)));

#define GAS __attribute__((address_space(1)))
#define LAS __attribute__((address_space(3)))

constexpr int D    = 1024;   // d_model
constexpr int ROWS = 8192;   // B*S

// ---------------------------------------------------------------- cast ----
__global__ __launch_bounds__(256) void cast_all(
    const float* __restrict__ x,
    const float* __restrict__ wq, const float* __restrict__ wk,
    const float* __restrict__ wv, const float* __restrict__ wo,
    bf16* __restrict__ xb, bf16* __restrict__ wqb, bf16* __restrict__ wkb,
    bf16* __restrict__ wvb, bf16* __restrict__ wob)
{
    int i = blockIdx.x * 256 + threadIdx.x;
    const float* src; bf16* dst; int off;
    if (i < 2 * 1024 * 1024) { src = x; dst = xb; off = i; }
    else {
        int j = i - 2 * 1024 * 1024;
        int w = j >> 18;
        off = j & ((1 << 18) - 1);
        src = (w == 0) ? wq : (w == 1) ? wk : (w == 2) ? wv : wo;
        dst = (w == 0) ? wqb : (w == 1) ? wkb : (w == 2) ? wvb : wob;
    }
    float4 v = ((const float4*)src)[off];
    v4bf o;
    o[0] = (bf16)v.x; o[1] = (bf16)v.y; o[2] = (bf16)v.z; o[3] = (bf16)v.w;
    ((v4bf*)dst)[off] = o;
}

// ---------------------------------------------------------------- GEMM ----
// Deep-pipelined C = A (ROWS x D) * W^T.  BM=256, BN=128, BK=64.
// 512 threads = 8 waves (4M x 2N), 64x64 output per wave, 16x16x32 MFMA.
// Triple-buffered LDS (144 KiB) filled by global_load_lds (width 16) with
// pre-swizzled SOURCE addresses (16B-chunk ^= row&7) so swizzled reads are
// conflict-free.  Counted vmcnt: per iter {stage t+2; compute t;
// s_waitcnt vmcnt(6); s_barrier} -- next tile's loads land while the tile
// after stays in flight across the barrier (never drain to 0 in the loop).
// MODE 0: W = [3072][1024] QKV concat; epilogue by col-range: Q scaled
//         bf16, K bf16, V transposed into VtG[b][h][d][s].
// MODE 1: W = wo; fp32 out + bias + residual X.
template<int MODE, int NTN>
__global__ __launch_bounds__(512, 2) void gemm8(
    const bf16* __restrict__ A, const bf16* __restrict__ W,
    bf16* __restrict__ Oq, bf16* __restrict__ Ok, bf16* __restrict__ Ov,
    float* __restrict__ Of, const float* __restrict__ bias,
    const float* __restrict__ X)
{
    __shared__ bf16 Abuf[3][256 * 64];   // 96 KiB
    __shared__ bf16 Bbuf[3][128 * 64];   // 48 KiB

    // XCD-chunked decode: consecutive wgid on one XCD share mTile (A panel).
    const int id   = blockIdx.x;
    const int wgid = (id & 7) * (4 * NTN) + (id >> 3);
    const int mT   = wgid / NTN;
    const int nT   = wgid - mT * NTN;
    const long rowA0 = (long)mT * 256;
    const long colB0 = (long)nT * 128;

    const int tid  = threadIdx.x;
    const int lane = tid & 63;
    const int wave = tid >> 6;
    const int quad = lane >> 4;
    const int l16  = lane & 15;
    const int wm   = (wave >> 1) * 64;   // 4 M-waves
    const int wn   = (wave & 1) * 64;    // 2 N-waves

    // staging source (pre-swizzled column)
    const int srow = wave * 8 + (lane >> 3);
    const int scol = ((lane & 7) ^ (lane >> 3)) * 8;
    const bf16* gA = A + (rowA0 + srow) * D + scol;
    const bf16* gB = W + (colB0 + srow) * D + scol;
    const int dstOff = wave * 512;       // elems; wave-uniform LDS base part

    auto stage = [&](int bi, int t) {
        const bf16* a = gA + (long)t * 64;
        const bf16* b = gB + (long)t * 64;
        #pragma unroll
        for (int i = 0; i < 4; i++)
            __builtin_amdgcn_global_load_lds(
                (const GAS void*)(a + (long)i * 64 * D),
                (LAS void*)(&Abuf[bi][i * 4096 + dstOff]), 16, 0, 0);
        #pragma unroll
        for (int i = 0; i < 2; i++)
            __builtin_amdgcn_global_load_lds(
                (const GAS void*)(b + (long)i * 64 * D),
                (LAS void*)(&Bbuf[bi][i * 4096 + dstOff]), 16, 0, 0);
    };

    const v4f vzero = {0.f, 0.f, 0.f, 0.f};
    v4f acc[4][4];
    #pragma unroll
    for (int i = 0; i < 4; i++)
        #pragma unroll
        for (int j = 0; j < 4; j++) acc[i][j] = vzero;

    // swizzled read offsets (elems): row*64 + ((ks*4+quad)^(l16&7))*8
    int sa[2], sb[2];
    #pragma unroll
    for (int ks = 0; ks < 2; ks++) {
        const int ch = ((ks * 4 + quad) ^ (l16 & 7)) * 8;
        sa[ks] = (wm + l16) * 64 + ch;
        sb[ks] = (wn + l16) * 64 + ch;
    }

    auto compute = [&](int bi) {
        const bf16* As = &Abuf[bi][0];
        const bf16* Bs = &Bbuf[bi][0];
        v8bf af[2][4], bf[2][4];
        #pragma unroll
        for (int ks = 0; ks < 2; ks++) {
            #pragma unroll
            for (int mi = 0; mi < 4; mi++)
                af[ks][mi] = *(const v8bf*)(As + sa[ks] + mi * 1024);
            #pragma unroll
            for (int ni = 0; ni < 4; ni++)
                bf[ks][ni] = *(const v8bf*)(Bs + sb[ks] + ni * 1024);
        }
        __builtin_amdgcn_s_setprio(1);
        #pragma unroll
        for (int ks = 0; ks < 2; ks++)
            #pragma unroll
            for (int mi = 0; mi < 4; mi++)
                #pragma unroll
                for (int ni = 0; ni < 4; ni++)
                    acc[mi][ni] = __builtin_amdgcn_mfma_f32_16x16x32_bf16(
                        af[ks][mi], bf[ks][ni], acc[mi][ni], 0, 0, 0);
        __builtin_amdgcn_s_setprio(0);
    };

    constexpr int NT = 16;   // K=1024 / BK=64
    stage(0, 0);
    stage(1, 1);
    asm volatile("s_waitcnt vmcnt(6)" ::: "memory");
    __builtin_amdgcn_s_barrier();

    for (int t = 0; t < NT; ++t) {
        if (t + 2 < NT) stage((t + 2) % 3, t + 2);
        compute(t % 3);
        if (t + 1 < NT) {
            if (t + 2 < NT) {
                asm volatile("s_waitcnt vmcnt(6)" ::: "memory");
            } else {
                asm volatile("s_waitcnt vmcnt(0)" ::: "memory");
            }
            __builtin_amdgcn_s_barrier();
        }
    }

    const float qscale = 0.125f * 1.44269504f;

    if (MODE == 0) {
        const int z = (int)(colB0 >> 10);
        #pragma unroll
        for (int mi = 0; mi < 4; mi++) {
            #pragma unroll
            for (int ni = 0; ni < 4; ni++) {
                const long col = colB0 + wn + ni * 16 + l16;
                const long c   = col & 1023;
                const long row0 = rowA0 + wm + mi * 16 + quad * 4;
                if (z == 2) {
                    const long h_ = c >> 6, dd = c & 63;
                    const long b_ = row0 >> 11, s0 = row0 & 2047;
                    v4bf pk;
                    #pragma unroll
                    for (int r = 0; r < 4; r++) pk[r] = (bf16)acc[mi][ni][r];
                    *(v4bf*)(Ov + ((b_ * 16 + h_) * 64 + dd) * 2048 + s0) = pk;
                } else {
                    bf16* Ob = (z == 0) ? Oq : Ok;
                    #pragma unroll
                    for (int r = 0; r < 4; r++) {
                        float v = acc[mi][ni][r];
                        if (z == 0) v *= qscale;
                        Ob[(row0 + r) * D + c] = (bf16)v;
                    }
                }
            }
        }
    } else {
        #pragma unroll
        for (int mi = 0; mi < 4; mi++) {
            #pragma unroll
            for (int ni = 0; ni < 4; ni++) {
                const long col = colB0 + wn + ni * 16 + l16;
                const float bv = bias[col];
                #pragma unroll
                for (int r = 0; r < 4; r++) {
                    const long row = rowA0 + wm + mi * 16 + quad * 4 + r;
                    Of[row * D + col] = acc[mi][ni][r] + bv + X[row * D + col];
                }
            }
        }
    }
}

// ----------------------------------------------------------- attention ----
// 512 blocks (XCD-grouped decode), 512 threads = 8 waves x 32 q-rows
// (q-tile 256). 32x32x16 MFMA, swapped QK^T, in-register P transpose
// (cvt_pk + permlane32_swap). 4-deep K/V LDS buffers: ONE barrier per
// 2 k-tiles; global loads issued a full 2-tile group ahead of their
// ds_write, which is a further group ahead of the reads. s_setprio(1)
// wraps each MFMA cluster (T5). XOR-swizzled LDS (16B-chunk ^= row&7).
__global__ __launch_bounds__(512, 4) void attn_kernel(
    const bf16* __restrict__ Q, const bf16* __restrict__ Kg,
    const bf16* __restrict__ VtG, bf16* __restrict__ O)
{
    const int id  = blockIdx.x;
    const int xcd = id & 7, j = id >> 3;
    const int qt  = j & 7;
    const int g   = xcd + 8 * (j >> 3);
    const int h   = g & 15, b = g >> 4;

    const int tid  = threadIdx.x;
    const int lane = tid & 63;
    const int wave = tid >> 6;
    const int l31  = lane & 31;
    const int hi   = lane >> 5;

    __shared__ bf16 Kt[4][64 * 64];   // K[kk][d], swizzled
    __shared__ bf16 Vt[4][64 * 64];   // V^T[d][kk], swizzled

    const long qrow = (long)(b * 2048 + qt * 256 + wave * 32 + l31);
    v8bf qB[4];
    #pragma unroll
    for (int f = 0; f < 4; f++)
        qB[f] = *(const v8bf*)(Q + qrow * D + h * 64 + f * 16 + hi * 8);

    const v16f z16 = {0.f,0.f,0.f,0.f,0.f,0.f,0.f,0.f,
                      0.f,0.f,0.f,0.f,0.f,0.f,0.f,0.f};
    v16f o_acc[2];
    o_acc[0] = z16; o_acc[1] = z16;
    float l0 = 0.f, l1 = 0.f;

    const int iR = tid >> 3;        // staging row 0..63
    const int c8 = tid & 7;         // 16B chunk 0..7
    const bf16* kLane = Kg  + (long)b * 2048 * D + h * 64 + c8 * 8 + (long)iR * D;
    const bf16* vLane = VtG + (long)(b * 16 + h) * 64 * 2048 + c8 * 8 + (long)iR * 2048;
    const int wOff = iR * 64 + ((c8 ^ (iR & 7)) * 8);   // swizzled write slot

    v8bf kp[2], vp[2];
    kp[0] = *(const v8bf*)(kLane); vp[0] = *(const v8bf*)(vLane);
    kLane += 64 * D; vLane += 64;
    kp[1] = *(const v8bf*)(kLane); vp[1] = *(const v8bf*)(vLane);
    kLane += 64 * D; vLane += 64;
    *(v8bf*)(&Kt[0][wOff]) = kp[0]; *(v8bf*)(&Vt[0][wOff]) = vp[0];
    *(v8bf*)(&Kt[1][wOff]) = kp[1]; *(v8bf*)(&Vt[1][wOff]) = vp[1];
    kp[0] = *(const v8bf*)(kLane); vp[0] = *(const v8bf*)(vLane);
    kLane += 64 * D; vLane += 64;
    kp[1] = *(const v8bf*)(kLane); vp[1] = *(const v8bf*)(vLane);
    kLane += 64 * D; vLane += 64;

    auto compute = [&](const int bq) {
        #pragma unroll
        for (int ko = 0; ko < 2; ko++) {
            const int krow = ko * 32 + l31;
            const int ksw  = krow & 7;
            v8bf kA[4];
            #pragma unroll
            for (int f = 0; f < 4; f++)
                kA[f] = *(const v8bf*)(&Kt[bq][krow * 64 + (((2 * f + hi) ^ ksw) * 8)]);
            __builtin_amdgcn_s_setprio(1);
            v16f st = __builtin_amdgcn_mfma_f32_32x32x16_bf16(kA[0], qB[0], z16, 0, 0, 0);
            st = __builtin_amdgcn_mfma_f32_32x32x16_bf16(kA[1], qB[1], st, 0, 0, 0);
            st = __builtin_amdgcn_mfma_f32_32x32x16_bf16(kA[2], qB[2], st, 0, 0, 0);
            st = __builtin_amdgcn_mfma_f32_32x32x16_bf16(kA[3], qB[3], st, 0, 0, 0);
            __builtin_amdgcn_s_setprio(0);

            float p[16];
            #pragma unroll
            for (int r = 0; r < 16; r++) {
                p[r] = __builtin_amdgcn_exp2f(st[r]);
                if (r & 1) l1 += p[r]; else l0 += p[r];
            }

            #pragma unroll
            for (int u = 0; u < 2; u++) {
                const int s = ko * 2 + u;
                u32 a0, a1, b0, b1;
                asm("v_cvt_pk_bf16_f32 %0, %1, %2" : "=v"(a0) : "v"(p[u*8+0]), "v"(p[u*8+1]));
                asm("v_cvt_pk_bf16_f32 %0, %1, %2" : "=v"(a1) : "v"(p[u*8+2]), "v"(p[u*8+3]));
                asm("v_cvt_pk_bf16_f32 %0, %1, %2" : "=v"(b0) : "v"(p[u*8+4]), "v"(p[u*8+5]));
                asm("v_cvt_pk_bf16_f32 %0, %1, %2" : "=v"(b1) : "v"(p[u*8+6]), "v"(p[u*8+7]));
                asm("v_permlane32_swap_b32 %0, %1" : "+v"(a0), "+v"(b0));
                asm("v_permlane32_swap_b32 %0, %1" : "+v"(a1), "+v"(b1));
                v4u w; w[0] = a0; w[1] = a1; w[2] = b0; w[3] = b1;
                const v8bf pa = __builtin_bit_cast(v8bf, w);
                const int vsw = (l31 & 7);
                v8bf vb0 = *(const v8bf*)(&Vt[bq][(l31)      * 64 + (((2 * s + hi) ^ vsw) * 8)]);
                v8bf vb1 = *(const v8bf*)(&Vt[bq][(32 + l31) * 64 + (((2 * s + hi) ^ vsw) * 8)]);
                __builtin_amdgcn_s_setprio(1);
                o_acc[0] = __builtin_amdgcn_mfma_f32_32x32x16_bf16(pa, vb0, o_acc[0], 0, 0, 0);
                o_acc[1] = __builtin_amdgcn_mfma_f32_32x32x16_bf16(pa, vb1, o_acc[1], 0, 0, 0);
                __builtin_amdgcn_s_setprio(0);
            }
        }
    };

    for (int gg = 0; gg < 16; ++gg) {
        const int cb = (gg & 1) * 2;
        __syncthreads();

        if (gg < 15) {
            *(v8bf*)(&Kt[cb ^ 2][wOff])       = kp[0];
            *(v8bf*)(&Vt[cb ^ 2][wOff])       = vp[0];
            *(v8bf*)(&Kt[(cb ^ 2) + 1][wOff]) = kp[1];
            *(v8bf*)(&Vt[(cb ^ 2) + 1][wOff]) = vp[1];
        }
        if (gg < 14) {
            kp[0] = *(const v8bf*)(kLane); vp[0] = *(const v8bf*)(vLane);
            kLane += 64 * D; vLane += 64;
            kp[1] = *(const v8bf*)(kLane); vp[1] = *(const v8bf*)(vLane);
            kLane += 64 * D; vLane += 64;
        }

        compute(cb);
        compute(cb + 1);
    }

    float l_acc = l0 + l1;
    l_acc += __shfl_xor(l_acc, 32);

    const long obase = (long)(b * 2048 + qt * 256 + wave * 32);
    #pragma unroll
    for (int r = 0; r < 16; r++) {
        const int qp = (r & 3) + 8 * (r >> 2) + 4 * hi;
        const float inv = 1.f / __shfl(l_acc, qp);
        O[(obase + qp) * D + h * 64 + l31]      = (bf16)(o_acc[0][r] * inv);
        O[(obase + qp) * D + h * 64 + 32 + l31] = (bf16)(o_acc[1][r] * inv);
    }
}

// ------------------------------------------------------------------ LN ----
__global__ __launch_bounds__(256) void ln_kernel(
    const float* __restrict__ g, const float* __restrict__ beta,
    float* __restrict__ out)
{
    const int row = blockIdx.x;
    const int t = threadIdx.x;
    const int lane = t & 63, wave = t >> 6;
    const long base = (long)row * D + t * 4;

    float4 yv = *(const float4*)(out + base);
    float y0 = yv.x, y1 = yv.y, y2 = yv.z, y3 = yv.w;
    float s1 = y0 + y1 + y2 + y3;
    float s2 = y0*y0 + y1*y1 + y2*y2 + y3*y3;
    #pragma unroll
    for (int off = 1; off < 64; off <<= 1) {
        s1 += __shfl_xor(s1, off);
        s2 += __shfl_xor(s2, off);
    }
    __shared__ float r1[4], r2[4];
    if (lane == 0) { r1[wave] = s1; r2[wave] = s2; }
    __syncthreads();
    float S1 = r1[0] + r1[1] + r1[2] + r1[3];
    float S2 = r2[0] + r2[1] + r2[2] + r2[3];
    float mu  = S1 * (1.f / 1024.f);
    float var = S2 * (1.f / 1024.f) - mu * mu;
    float rsd = rsqrtf(var + 1e-5f);

    float4 gv = *(const float4*)(g + t * 4);
    float4 bv = *(const float4*)(beta + t * 4);
    float4 o;
    o.x = (y0 - mu) * rsd * gv.x + bv.x;
    o.y = (y1 - mu) * rsd * gv.y + bv.y;
    o.z = (y2 - mu) * rsd * gv.z + bv.z;
    o.w = (y3 - mu) * rsd * gv.w + bv.w;
    *(float4*)(out + base) = o;
}

// ---------------------------------------------------------------- launch --
extern "C" void kernel_launch(void* const* d_in, const int* in_sizes, int n_in,
                              void* d_out, int out_size, void* d_ws, size_t ws_size,
                              hipStream_t stream)
{
    const float* x   = (const float*)d_in[0];
    const float* wq  = (const float*)d_in[1];
    const float* wk  = (const float*)d_in[2];
    const float* wv  = (const float*)d_in[3];
    const float* wo  = (const float*)d_in[4];
    const float* bo  = (const float*)d_in[5];
    const float* lng = (const float*)d_in[6];
    const float* lnb = (const float*)d_in[7];
    float* out = (float*)d_out;

    char* ws = (char*)d_ws;
    bf16* xb  = (bf16*)(ws);                            // 16 MiB
    bf16* wqb = (bf16*)(ws + (size_t)16 * 1024 * 1024); // 4 x 2 MiB (contig QKV,O)
    bf16* wkb = wqb + 1024 * 1024;
    bf16* wvb = wkb + 1024 * 1024;
    bf16* wob = wvb + 1024 * 1024;
    bf16* Qb  = (bf16*)(ws + (size_t)24 * 1024 * 1024); // 4 x 16 MiB
    bf16* Kb  = Qb + (size_t)ROWS * D;
    bf16* VtG = Kb + (size_t)ROWS * D;                  // V transposed [b][h][d][s]
    bf16* Ab  = VtG + (size_t)ROWS * D;                 // total 88 MiB

    cast_all<<<12288, 256, 0, stream>>>(x, wq, wk, wv, wo,
                                        xb, wqb, wkb, wvb, wob);

    // QKV: one dispatch, W = [3072][1024] (wq|wk|wv contiguous). 768 blocks
    // = exactly 3 rounds of 256 CUs at 1 block/CU.
    gemm8<0, 24><<<768, 512, 0, stream>>>(xb, wqb, Qb, Kb, VtG,
                                          nullptr, nullptr, nullptr);

    attn_kernel<<<dim3(512, 1, 1), 512, 0, stream>>>(Qb, Kb, VtG, Ab);

    // Output proj: 256 blocks = exactly 1 full round.
    gemm8<1, 8><<<256, 512, 0, stream>>>(Ab, wob, nullptr, nullptr, nullptr,
                                         out, bo, x);

    ln_kernel<<<8192, 256, 0, stream>>>(lng, lnb, out);
}

// Round 5
// 278.577 us; speedup vs baseline: 1.0763x; 1.0763x over previous
//
#include <hip/hip_runtime.h>

typedef __bf16 bf16;
typedef bf16 v8bf __attribute__((ext_vector_type(8)));
typedef bf16 v4bf __attribute__((ext_vector_type(4)));
typedef float v4f __attribute__((ext_vector_type(4)));
typedef float v16f __attribute__((ext_vector_type(16)));
typedef unsigned int u32;
typedef u32 v4u __attribute__((ext_vector_type(4)));

#define GAS __attribute__((address_space(1)))
#define LAS __attribute__((address_space(3)))

constexpr int D    = 1024;   // d_model
constexpr int ROWS = 8192;   // B*S

// ---------------------------------------------------------------- cast ----
__global__ __launch_bounds__(256) void cast_all(
    const float* __restrict__ x,
    const float* __restrict__ wq, const float* __restrict__ wk,
    const float* __restrict__ wv, const float* __restrict__ wo,
    bf16* __restrict__ xb, bf16* __restrict__ wqb, bf16* __restrict__ wkb,
    bf16* __restrict__ wvb, bf16* __restrict__ wob)
{
    int i = blockIdx.x * 256 + threadIdx.x;
    const float* src; bf16* dst; int off;
    if (i < 2 * 1024 * 1024) { src = x; dst = xb; off = i; }
    else {
        int j = i - 2 * 1024 * 1024;
        int w = j >> 18;
        off = j & ((1 << 18) - 1);
        src = (w == 0) ? wq : (w == 1) ? wk : (w == 2) ? wv : wo;
        dst = (w == 0) ? wqb : (w == 1) ? wkb : (w == 2) ? wvb : wob;
    }
    float4 v = ((const float4*)src)[off];
    v4bf o;
    o[0] = (bf16)v.x; o[1] = (bf16)v.y; o[2] = (bf16)v.z; o[3] = (bf16)v.w;
    ((v4bf*)dst)[off] = o;
}

// ---------------------------------------------------------------- GEMM ----
// Deep-pipelined C = A (ROWS x D) * W^T.  BM=256, BN=128, BK=64.
// 512 threads = 8 waves (4M x 2N), 64x64 output per wave, 16x16x32 MFMA.
// Triple-buffered LDS (144 KiB) filled by global_load_lds (width 16) with
// pre-swizzled SOURCE addresses (16B-chunk ^= row&7): swizzled reads are
// conflict-free (measured 0 last round).
// K-loop: per K-tile, TWO phases (one per k-half). Each phase:
//   8 ds_read_b128 (this half's frags) ; 3 global_load_lds (tile t+2)
//   [vmcnt(6) once per tile]  ; s_barrier ; lgkmcnt(0) ; setprio(1)
//   16 MFMA ; setprio(0) ; s_barrier
// Fine phase granularity lets waves micro-stagger inside the phase (first
// wave past its own lgkm enters MFMA while others still read) -- the m201
// lever. Ring/vmcnt semantics identical to the verified r4 kernel.
// MODE 0: W = [3072][1024] QKV concat; epilogue by col-range: Q scaled
//         bf16, K bf16, V transposed into VtG[b][h][d][s].
// MODE 1: W = wo; fp32 out + bias + residual X.
template<int MODE, int NTN>
__global__ __launch_bounds__(512, 2) void gemm8(
    const bf16* __restrict__ A, const bf16* __restrict__ W,
    bf16* __restrict__ Oq, bf16* __restrict__ Ok, bf16* __restrict__ Ov,
    float* __restrict__ Of, const float* __restrict__ bias,
    const float* __restrict__ X)
{
    __shared__ bf16 Abuf[3][256 * 64];   // 96 KiB
    __shared__ bf16 Bbuf[3][128 * 64];   // 48 KiB

    // XCD-chunked decode: consecutive wgid on one XCD share mTile (A panel).
    const int id   = blockIdx.x;
    const int wgid = (id & 7) * (4 * NTN) + (id >> 3);
    const int mT   = wgid / NTN;
    const int nT   = wgid - mT * NTN;
    const long rowA0 = (long)mT * 256;
    const long colB0 = (long)nT * 128;

    const int tid  = threadIdx.x;
    const int lane = tid & 63;
    const int wave = tid >> 6;
    const int quad = lane >> 4;
    const int l16  = lane & 15;
    const int wm   = (wave >> 1) * 64;   // 4 M-waves
    const int wn   = (wave & 1) * 64;    // 2 N-waves

    // staging source (pre-swizzled column)
    const int srow = wave * 8 + (lane >> 3);
    const int scol = ((lane & 7) ^ (lane >> 3)) * 8;
    const bf16* gA = A + (rowA0 + srow) * D + scol;
    const bf16* gB = W + (colB0 + srow) * D + scol;
    const int dstOff = wave * 512;       // elems; wave-uniform LDS base part

    const v4f vzero = {0.f, 0.f, 0.f, 0.f};
    v4f acc[4][4];
    #pragma unroll
    for (int i = 0; i < 4; i++)
        #pragma unroll
        for (int j = 0; j < 4; j++) acc[i][j] = vzero;

    // swizzled read offsets (elems): row*64 + ((ks*4+quad)^(l16&7))*8
    int sa[2], sb[2];
    #pragma unroll
    for (int ks = 0; ks < 2; ks++) {
        const int ch = ((ks * 4 + quad) ^ (l16 & 7)) * 8;
        sa[ks] = (wm + l16) * 64 + ch;
        sb[ks] = (wn + l16) * 64 + ch;
    }

    auto stage_full = [&](int bi, int t) {
        const bf16* a = gA + (long)t * 64;
        const bf16* b = gB + (long)t * 64;
        #pragma unroll
        for (int i = 0; i < 4; i++)
            __builtin_amdgcn_global_load_lds(
                (const GAS void*)(a + (long)i * 64 * D),
                (LAS void*)(&Abuf[bi][i * 4096 + dstOff]), 16, 0, 0);
        #pragma unroll
        for (int i = 0; i < 2; i++)
            __builtin_amdgcn_global_load_lds(
                (const GAS void*)(b + (long)i * 64 * D),
                (LAS void*)(&Bbuf[bi][i * 4096 + dstOff]), 16, 0, 0);
    };

    constexpr int NT = 16;   // K=1024 / BK=64
    stage_full(0, 0);
    stage_full(1, 1);
    asm volatile("s_waitcnt vmcnt(6)" ::: "memory");
    __builtin_amdgcn_s_barrier();

    for (int t = 0; t < NT; ++t) {
        const int bi = t % 3;
        const int bs = (t + 2) % 3;
        const bf16* As = &Abuf[bi][0];
        const bf16* Bs = &Bbuf[bi][0];
        #pragma unroll
        for (int ks = 0; ks < 2; ++ks) {
            // this phase's fragments (8 x ds_read_b128)
            v8bf af[4], bf4[4];
            #pragma unroll
            for (int mi = 0; mi < 4; mi++)
                af[mi] = *(const v8bf*)(As + sa[ks] + mi * 1024);
            #pragma unroll
            for (int ni = 0; ni < 4; ni++)
                bf4[ni] = *(const v8bf*)(Bs + sb[ks] + ni * 1024);

            // stage half of tile t+2 (3 x global_load_lds)
            if (t + 2 < NT) {
                const bf16* a2 = gA + (long)(t + 2) * 64;
                const bf16* b2 = gB + (long)(t + 2) * 64;
                if (ks == 0) {
                    __builtin_amdgcn_global_load_lds(
                        (const GAS void*)(a2),
                        (LAS void*)(&Abuf[bs][dstOff]), 16, 0, 0);
                    __builtin_amdgcn_global_load_lds(
                        (const GAS void*)(a2 + (long)64 * D),
                        (LAS void*)(&Abuf[bs][4096 + dstOff]), 16, 0, 0);
                    __builtin_amdgcn_global_load_lds(
                        (const GAS void*)(b2),
                        (LAS void*)(&Bbuf[bs][dstOff]), 16, 0, 0);
                } else {
                    __builtin_amdgcn_global_load_lds(
                        (const GAS void*)(a2 + (long)128 * D),
                        (LAS void*)(&Abuf[bs][2 * 4096 + dstOff]), 16, 0, 0);
                    __builtin_amdgcn_global_load_lds(
                        (const GAS void*)(a2 + (long)192 * D),
                        (LAS void*)(&Abuf[bs][3 * 4096 + dstOff]), 16, 0, 0);
                    __builtin_amdgcn_global_load_lds(
                        (const GAS void*)(b2 + (long)64 * D),
                        (LAS void*)(&Bbuf[bs][4096 + dstOff]), 16, 0, 0);
                }
            }

            // once per tile: make buf[t+1] ready before crossing into it
            if (ks == 1 && t + 1 < NT) {
                if (t + 2 < NT) asm volatile("s_waitcnt vmcnt(6)" ::: "memory");
                else            asm volatile("s_waitcnt vmcnt(0)" ::: "memory");
            }

            __builtin_amdgcn_s_barrier();
            asm volatile("s_waitcnt lgkmcnt(0)" ::: "memory");
            __builtin_amdgcn_sched_barrier(0);
            __builtin_amdgcn_s_setprio(1);
            #pragma unroll
            for (int mi = 0; mi < 4; mi++)
                #pragma unroll
                for (int ni = 0; ni < 4; ni++)
                    acc[mi][ni] = __builtin_amdgcn_mfma_f32_16x16x32_bf16(
                        af[mi], bf4[ni], acc[mi][ni], 0, 0, 0);
            __builtin_amdgcn_s_setprio(0);
            __builtin_amdgcn_s_barrier();
        }
    }

    const float qscale = 0.125f * 1.44269504f;

    if (MODE == 0) {
        const int z = (int)(colB0 >> 10);
        #pragma unroll
        for (int mi = 0; mi < 4; mi++) {
            #pragma unroll
            for (int ni = 0; ni < 4; ni++) {
                const long col = colB0 + wn + ni * 16 + l16;
                const long c   = col & 1023;
                const long row0 = rowA0 + wm + mi * 16 + quad * 4;
                if (z == 2) {
                    const long h_ = c >> 6, dd = c & 63;
                    const long b_ = row0 >> 11, s0 = row0 & 2047;
                    v4bf pk;
                    #pragma unroll
                    for (int r = 0; r < 4; r++) pk[r] = (bf16)acc[mi][ni][r];
                    *(v4bf*)(Ov + ((b_ * 16 + h_) * 64 + dd) * 2048 + s0) = pk;
                } else {
                    bf16* Ob = (z == 0) ? Oq : Ok;
                    #pragma unroll
                    for (int r = 0; r < 4; r++) {
                        float v = acc[mi][ni][r];
                        if (z == 0) v *= qscale;
                        Ob[(row0 + r) * D + c] = (bf16)v;
                    }
                }
            }
        }
    } else {
        #pragma unroll
        for (int mi = 0; mi < 4; mi++) {
            #pragma unroll
            for (int ni = 0; ni < 4; ni++) {
                const long col = colB0 + wn + ni * 16 + l16;
                const float bv = bias[col];
                #pragma unroll
                for (int r = 0; r < 4; r++) {
                    const long row = rowA0 + wm + mi * 16 + quad * 4 + r;
                    Of[row * D + col] = acc[mi][ni][r] + bv + X[row * D + col];
                }
            }
        }
    }
}

// ----------------------------------------------------------- attention ----
// 512 blocks (XCD-grouped decode), 512 threads = 8 waves x 32 q-rows
// (q-tile 256). 32x32x16 MFMA, swapped QK^T, in-register P transpose
// (cvt_pk + permlane32_swap). 4-deep K/V LDS buffers: ONE barrier per
// 2 k-tiles; global loads issued a full 2-tile group ahead of their
// ds_write, which is a further group ahead of the reads. s_setprio(1)
// wraps each MFMA cluster (T5). XOR-swizzled LDS (16B-chunk ^= row&7).
__global__ __launch_bounds__(512, 4) void attn_kernel(
    const bf16* __restrict__ Q, const bf16* __restrict__ Kg,
    const bf16* __restrict__ VtG, bf16* __restrict__ O)
{
    const int id  = blockIdx.x;
    const int xcd = id & 7, j = id >> 3;
    const int qt  = j & 7;
    const int g   = xcd + 8 * (j >> 3);
    const int h   = g & 15, b = g >> 4;

    const int tid  = threadIdx.x;
    const int lane = tid & 63;
    const int wave = tid >> 6;
    const int l31  = lane & 31;
    const int hi   = lane >> 5;

    __shared__ bf16 Kt[4][64 * 64];   // K[kk][d], swizzled
    __shared__ bf16 Vt[4][64 * 64];   // V^T[d][kk], swizzled

    const long qrow = (long)(b * 2048 + qt * 256 + wave * 32 + l31);
    v8bf qB[4];
    #pragma unroll
    for (int f = 0; f < 4; f++)
        qB[f] = *(const v8bf*)(Q + qrow * D + h * 64 + f * 16 + hi * 8);

    const v16f z16 = {0.f,0.f,0.f,0.f,0.f,0.f,0.f,0.f,
                      0.f,0.f,0.f,0.f,0.f,0.f,0.f,0.f};
    v16f o_acc[2];
    o_acc[0] = z16; o_acc[1] = z16;
    float l0 = 0.f, l1 = 0.f;

    const int iR = tid >> 3;        // staging row 0..63
    const int c8 = tid & 7;         // 16B chunk 0..7
    const bf16* kLane = Kg  + (long)b * 2048 * D + h * 64 + c8 * 8 + (long)iR * D;
    const bf16* vLane = VtG + (long)(b * 16 + h) * 64 * 2048 + c8 * 8 + (long)iR * 2048;
    const int wOff = iR * 64 + ((c8 ^ (iR & 7)) * 8);   // swizzled write slot

    v8bf kp[2], vp[2];
    kp[0] = *(const v8bf*)(kLane); vp[0] = *(const v8bf*)(vLane);
    kLane += 64 * D; vLane += 64;
    kp[1] = *(const v8bf*)(kLane); vp[1] = *(const v8bf*)(vLane);
    kLane += 64 * D; vLane += 64;
    *(v8bf*)(&Kt[0][wOff]) = kp[0]; *(v8bf*)(&Vt[0][wOff]) = vp[0];
    *(v8bf*)(&Kt[1][wOff]) = kp[1]; *(v8bf*)(&Vt[1][wOff]) = vp[1];
    kp[0] = *(const v8bf*)(kLane); vp[0] = *(const v8bf*)(vLane);
    kLane += 64 * D; vLane += 64;
    kp[1] = *(const v8bf*)(kLane); vp[1] = *(const v8bf*)(vLane);
    kLane += 64 * D; vLane += 64;

    auto compute = [&](const int bq) {
        #pragma unroll
        for (int ko = 0; ko < 2; ko++) {
            const int krow = ko * 32 + l31;
            const int ksw  = krow & 7;
            v8bf kA[4];
            #pragma unroll
            for (int f = 0; f < 4; f++)
                kA[f] = *(const v8bf*)(&Kt[bq][krow * 64 + (((2 * f + hi) ^ ksw) * 8)]);
            __builtin_amdgcn_s_setprio(1);
            v16f st = __builtin_amdgcn_mfma_f32_32x32x16_bf16(kA[0], qB[0], z16, 0, 0, 0);
            st = __builtin_amdgcn_mfma_f32_32x32x16_bf16(kA[1], qB[1], st, 0, 0, 0);
            st = __builtin_amdgcn_mfma_f32_32x32x16_bf16(kA[2], qB[2], st, 0, 0, 0);
            st = __builtin_amdgcn_mfma_f32_32x32x16_bf16(kA[3], qB[3], st, 0, 0, 0);
            __builtin_amdgcn_s_setprio(0);

            float p[16];
            #pragma unroll
            for (int r = 0; r < 16; r++) {
                p[r] = __builtin_amdgcn_exp2f(st[r]);
                if (r & 1) l1 += p[r]; else l0 += p[r];
            }

            #pragma unroll
            for (int u = 0; u < 2; u++) {
                const int s = ko * 2 + u;
                u32 a0, a1, b0, b1;
                asm("v_cvt_pk_bf16_f32 %0, %1, %2" : "=v"(a0) : "v"(p[u*8+0]), "v"(p[u*8+1]));
                asm("v_cvt_pk_bf16_f32 %0, %1, %2" : "=v"(a1) : "v"(p[u*8+2]), "v"(p[u*8+3]));
                asm("v_cvt_pk_bf16_f32 %0, %1, %2" : "=v"(b0) : "v"(p[u*8+4]), "v"(p[u*8+5]));
                asm("v_cvt_pk_bf16_f32 %0, %1, %2" : "=v"(b1) : "v"(p[u*8+6]), "v"(p[u*8+7]));
                asm("v_permlane32_swap_b32 %0, %1" : "+v"(a0), "+v"(b0));
                asm("v_permlane32_swap_b32 %0, %1" : "+v"(a1), "+v"(b1));
                v4u w; w[0] = a0; w[1] = a1; w[2] = b0; w[3] = b1;
                const v8bf pa = __builtin_bit_cast(v8bf, w);
                const int vsw = (l31 & 7);
                v8bf vb0 = *(const v8bf*)(&Vt[bq][(l31)      * 64 + (((2 * s + hi) ^ vsw) * 8)]);
                v8bf vb1 = *(const v8bf*)(&Vt[bq][(32 + l31) * 64 + (((2 * s + hi) ^ vsw) * 8)]);
                __builtin_amdgcn_s_setprio(1);
                o_acc[0] = __builtin_amdgcn_mfma_f32_32x32x16_bf16(pa, vb0, o_acc[0], 0, 0, 0);
                o_acc[1] = __builtin_amdgcn_mfma_f32_32x32x16_bf16(pa, vb1, o_acc[1], 0, 0, 0);
                __builtin_amdgcn_s_setprio(0);
            }
        }
    };

    for (int gg = 0; gg < 16; ++gg) {
        const int cb = (gg & 1) * 2;
        __syncthreads();

        if (gg < 15) {
            *(v8bf*)(&Kt[cb ^ 2][wOff])       = kp[0];
            *(v8bf*)(&Vt[cb ^ 2][wOff])       = vp[0];
            *(v8bf*)(&Kt[(cb ^ 2) + 1][wOff]) = kp[1];
            *(v8bf*)(&Vt[(cb ^ 2) + 1][wOff]) = vp[1];
        }
        if (gg < 14) {
            kp[0] = *(const v8bf*)(kLane); vp[0] = *(const v8bf*)(vLane);
            kLane += 64 * D; vLane += 64;
            kp[1] = *(const v8bf*)(kLane); vp[1] = *(const v8bf*)(vLane);
            kLane += 64 * D; vLane += 64;
        }

        compute(cb);
        compute(cb + 1);
    }

    float l_acc = l0 + l1;
    l_acc += __shfl_xor(l_acc, 32);

    const long obase = (long)(b * 2048 + qt * 256 + wave * 32);
    #pragma unroll
    for (int r = 0; r < 16; r++) {
        const int qp = (r & 3) + 8 * (r >> 2) + 4 * hi;
        const float inv = 1.f / __shfl(l_acc, qp);
        O[(obase + qp) * D + h * 64 + l31]      = (bf16)(o_acc[0][r] * inv);
        O[(obase + qp) * D + h * 64 + 32 + l31] = (bf16)(o_acc[1][r] * inv);
    }
}

// ------------------------------------------------------------------ LN ----
__global__ __launch_bounds__(256) void ln_kernel(
    const float* __restrict__ g, const float* __restrict__ beta,
    float* __restrict__ out)
{
    const int row = blockIdx.x;
    const int t = threadIdx.x;
    const int lane = t & 63, wave = t >> 6;
    const long base = (long)row * D + t * 4;

    float4 yv = *(const float4*)(out + base);
    float y0 = yv.x, y1 = yv.y, y2 = yv.z, y3 = yv.w;
    float s1 = y0 + y1 + y2 + y3;
    float s2 = y0*y0 + y1*y1 + y2*y2 + y3*y3;
    #pragma unroll
    for (int off = 1; off < 64; off <<= 1) {
        s1 += __shfl_xor(s1, off);
        s2 += __shfl_xor(s2, off);
    }
    __shared__ float r1[4], r2[4];
    if (lane == 0) { r1[wave] = s1; r2[wave] = s2; }
    __syncthreads();
    float S1 = r1[0] + r1[1] + r1[2] + r1[3];
    float S2 = r2[0] + r2[1] + r2[2] + r2[3];
    float mu  = S1 * (1.f / 1024.f);
    float var = S2 * (1.f / 1024.f) - mu * mu;
    float rsd = rsqrtf(var + 1e-5f);

    float4 gv = *(const float4*)(g + t * 4);
    float4 bv = *(const float4*)(beta + t * 4);
    float4 o;
    o.x = (y0 - mu) * rsd * gv.x + bv.x;
    o.y = (y1 - mu) * rsd * gv.y + bv.y;
    o.z = (y2 - mu) * rsd * gv.z + bv.z;
    o.w = (y3 - mu) * rsd * gv.w + bv.w;
    *(float4*)(out + base) = o;
}

// ---------------------------------------------------------------- launch --
extern "C" void kernel_launch(void* const* d_in, const int* in_sizes, int n_in,
                              void* d_out, int out_size, void* d_ws, size_t ws_size,
                              hipStream_t stream)
{
    const float* x   = (const float*)d_in[0];
    const float* wq  = (const float*)d_in[1];
    const float* wk  = (const float*)d_in[2];
    const float* wv  = (const float*)d_in[3];
    const float* wo  = (const float*)d_in[4];
    const float* bo  = (const float*)d_in[5];
    const float* lng = (const float*)d_in[6];
    const float* lnb = (const float*)d_in[7];
    float* out = (float*)d_out;

    char* ws = (char*)d_ws;
    bf16* xb  = (bf16*)(ws);                            // 16 MiB
    bf16* wqb = (bf16*)(ws + (size_t)16 * 1024 * 1024); // 4 x 2 MiB (contig QKV,O)
    bf16* wkb = wqb + 1024 * 1024;
    bf16* wvb = wkb + 1024 * 1024;
    bf16* wob = wvb + 1024 * 1024;
    bf16* Qb  = (bf16*)(ws + (size_t)24 * 1024 * 1024); // 4 x 16 MiB
    bf16* Kb  = Qb + (size_t)ROWS * D;
    bf16* VtG = Kb + (size_t)ROWS * D;                  // V transposed [b][h][d][s]
    bf16* Ab  = VtG + (size_t)ROWS * D;                 // total 88 MiB

    cast_all<<<12288, 256, 0, stream>>>(x, wq, wk, wv, wo,
                                        xb, wqb, wkb, wvb, wob);

    // QKV: one dispatch, W = [3072][1024] (wq|wk|wv contiguous). 768 blocks
    // = exactly 3 rounds of 256 CUs at 1 block/CU.
    gemm8<0, 24><<<768, 512, 0, stream>>>(xb, wqb, Qb, Kb, VtG,
                                          nullptr, nullptr, nullptr);

    attn_kernel<<<dim3(512, 1, 1), 512, 0, stream>>>(Qb, Kb, VtG, Ab);

    // Output proj: 256 blocks = exactly 1 full round.
    gemm8<1, 8><<<256, 512, 0, stream>>>(Ab, wob, nullptr, nullptr, nullptr,
                                         out, bo, x);

    ln_kernel<<<8192, 256, 0, stream>>>(lng, lnb, out);
}

// Round 6
// 278.237 us; speedup vs baseline: 1.0776x; 1.0012x over previous
//
#include <hip/hip_runtime.h>

typedef __bf16 bf16;
typedef bf16 v8bf __attribute__((ext_vector_type(8)));
typedef bf16 v4bf __attribute__((ext_vector_type(4)));
typedef float v4f __attribute__((ext_vector_type(4)));
typedef float v16f __attribute__((ext_vector_type(16)));
typedef unsigned int u32;
typedef u32 v4u __attribute__((ext_vector_type(4)));

#define GAS __attribute__((address_space(1)))
#define LAS __attribute__((address_space(3)))

constexpr int D    = 1024;   // d_model
constexpr int ROWS = 8192;   // B*S

// ---------------------------------------------------------------- cast ----
__global__ __launch_bounds__(256) void cast_all(
    const float* __restrict__ x,
    const float* __restrict__ wq, const float* __restrict__ wk,
    const float* __restrict__ wv, const float* __restrict__ wo,
    bf16* __restrict__ xb, bf16* __restrict__ wqb, bf16* __restrict__ wkb,
    bf16* __restrict__ wvb, bf16* __restrict__ wob)
{
    int i = blockIdx.x * 256 + threadIdx.x;
    const float* src; bf16* dst; int off;
    if (i < 2 * 1024 * 1024) { src = x; dst = xb; off = i; }
    else {
        int j = i - 2 * 1024 * 1024;
        int w = j >> 18;
        off = j & ((1 << 18) - 1);
        src = (w == 0) ? wq : (w == 1) ? wk : (w == 2) ? wv : wo;
        dst = (w == 0) ? wqb : (w == 1) ? wkb : (w == 2) ? wvb : wob;
    }
    float4 v = ((const float4*)src)[off];
    v4bf o;
    o[0] = (bf16)v.x; o[1] = (bf16)v.y; o[2] = (bf16)v.z; o[3] = (bf16)v.w;
    ((v4bf*)dst)[off] = o;
}

// ---------------------------------------------------------------- GEMM ----
// Deep-pipelined C = A (ROWS x D) * W^T.  BM=256, BN=128, BK=64.
// 512 threads = 8 waves (4M x 2N), 64x64 output per wave, 16x16x32 MFMA.
// Triple-buffered LDS (144 KiB) filled by global_load_lds (width 16) with
// pre-swizzled SOURCE addresses (16B-chunk ^= row&7): swizzled reads are
// conflict-free (measured 0).
// K-loop: per K-tile, TWO phases (one per k-half). Each phase:
//   8 ds_read_b128 ; 3 global_load_lds (tile t+2) ; [vmcnt(6) once/tile]
//   s_barrier ; lgkmcnt(0) ; setprio(1) 16 MFMA setprio(0) ; s_barrier
// MODE 0: W = [3072][1024] QKV concat; epilogue by col-range: Q scaled
//         bf16, K bf16, V transposed into VtG[b][h][d][s].
// MODE 1: W = wo; fp32 out + bias + residual X.
template<int MODE, int NTN>
__global__ __launch_bounds__(512, 2) void gemm8(
    const bf16* __restrict__ A, const bf16* __restrict__ W,
    bf16* __restrict__ Oq, bf16* __restrict__ Ok, bf16* __restrict__ Ov,
    float* __restrict__ Of, const float* __restrict__ bias,
    const float* __restrict__ X)
{
    __shared__ bf16 Abuf[3][256 * 64];   // 96 KiB
    __shared__ bf16 Bbuf[3][128 * 64];   // 48 KiB

    // XCD-chunked decode: consecutive wgid on one XCD share mTile (A panel).
    const int id   = blockIdx.x;
    const int wgid = (id & 7) * (4 * NTN) + (id >> 3);
    const int mT   = wgid / NTN;
    const int nT   = wgid - mT * NTN;
    const long rowA0 = (long)mT * 256;
    const long colB0 = (long)nT * 128;

    const int tid  = threadIdx.x;
    const int lane = tid & 63;
    const int wave = tid >> 6;
    const int quad = lane >> 4;
    const int l16  = lane & 15;
    const int wm   = (wave >> 1) * 64;   // 4 M-waves
    const int wn   = (wave & 1) * 64;    // 2 N-waves

    // staging source (pre-swizzled column)
    const int srow = wave * 8 + (lane >> 3);
    const int scol = ((lane & 7) ^ (lane >> 3)) * 8;
    const bf16* gA = A + (rowA0 + srow) * D + scol;
    const bf16* gB = W + (colB0 + srow) * D + scol;
    const int dstOff = wave * 512;       // elems; wave-uniform LDS base part

    const v4f vzero = {0.f, 0.f, 0.f, 0.f};
    v4f acc[4][4];
    #pragma unroll
    for (int i = 0; i < 4; i++)
        #pragma unroll
        for (int j = 0; j < 4; j++) acc[i][j] = vzero;

    // swizzled read offsets (elems): row*64 + ((ks*4+quad)^(l16&7))*8
    int sa[2], sb[2];
    #pragma unroll
    for (int ks = 0; ks < 2; ks++) {
        const int ch = ((ks * 4 + quad) ^ (l16 & 7)) * 8;
        sa[ks] = (wm + l16) * 64 + ch;
        sb[ks] = (wn + l16) * 64 + ch;
    }

    auto stage_full = [&](int bi, int t) {
        const bf16* a = gA + (long)t * 64;
        const bf16* b = gB + (long)t * 64;
        #pragma unroll
        for (int i = 0; i < 4; i++)
            __builtin_amdgcn_global_load_lds(
                (const GAS void*)(a + (long)i * 64 * D),
                (LAS void*)(&Abuf[bi][i * 4096 + dstOff]), 16, 0, 0);
        #pragma unroll
        for (int i = 0; i < 2; i++)
            __builtin_amdgcn_global_load_lds(
                (const GAS void*)(b + (long)i * 64 * D),
                (LAS void*)(&Bbuf[bi][i * 4096 + dstOff]), 16, 0, 0);
    };

    constexpr int NT = 16;   // K=1024 / BK=64
    stage_full(0, 0);
    stage_full(1, 1);
    asm volatile("s_waitcnt vmcnt(6)" ::: "memory");
    __builtin_amdgcn_s_barrier();

    for (int t = 0; t < NT; ++t) {
        const int bi = t % 3;
        const int bs = (t + 2) % 3;
        const bf16* As = &Abuf[bi][0];
        const bf16* Bs = &Bbuf[bi][0];
        #pragma unroll
        for (int ks = 0; ks < 2; ++ks) {
            // this phase's fragments (8 x ds_read_b128)
            v8bf af[4], bf4[4];
            #pragma unroll
            for (int mi = 0; mi < 4; mi++)
                af[mi] = *(const v8bf*)(As + sa[ks] + mi * 1024);
            #pragma unroll
            for (int ni = 0; ni < 4; ni++)
                bf4[ni] = *(const v8bf*)(Bs + sb[ks] + ni * 1024);

            // stage half of tile t+2 (3 x global_load_lds)
            if (t + 2 < NT) {
                const bf16* a2 = gA + (long)(t + 2) * 64;
                const bf16* b2 = gB + (long)(t + 2) * 64;
                if (ks == 0) {
                    __builtin_amdgcn_global_load_lds(
                        (const GAS void*)(a2),
                        (LAS void*)(&Abuf[bs][dstOff]), 16, 0, 0);
                    __builtin_amdgcn_global_load_lds(
                        (const GAS void*)(a2 + (long)64 * D),
                        (LAS void*)(&Abuf[bs][4096 + dstOff]), 16, 0, 0);
                    __builtin_amdgcn_global_load_lds(
                        (const GAS void*)(b2),
                        (LAS void*)(&Bbuf[bs][dstOff]), 16, 0, 0);
                } else {
                    __builtin_amdgcn_global_load_lds(
                        (const GAS void*)(a2 + (long)128 * D),
                        (LAS void*)(&Abuf[bs][2 * 4096 + dstOff]), 16, 0, 0);
                    __builtin_amdgcn_global_load_lds(
                        (const GAS void*)(a2 + (long)192 * D),
                        (LAS void*)(&Abuf[bs][3 * 4096 + dstOff]), 16, 0, 0);
                    __builtin_amdgcn_global_load_lds(
                        (const GAS void*)(b2 + (long)64 * D),
                        (LAS void*)(&Bbuf[bs][4096 + dstOff]), 16, 0, 0);
                }
            }

            // once per tile: make buf[t+1] ready before crossing into it
            if (ks == 1 && t + 1 < NT) {
                if (t + 2 < NT) asm volatile("s_waitcnt vmcnt(6)" ::: "memory");
                else            asm volatile("s_waitcnt vmcnt(0)" ::: "memory");
            }

            __builtin_amdgcn_s_barrier();
            asm volatile("s_waitcnt lgkmcnt(0)" ::: "memory");
            __builtin_amdgcn_sched_barrier(0);
            __builtin_amdgcn_s_setprio(1);
            #pragma unroll
            for (int mi = 0; mi < 4; mi++)
                #pragma unroll
                for (int ni = 0; ni < 4; ni++)
                    acc[mi][ni] = __builtin_amdgcn_mfma_f32_16x16x32_bf16(
                        af[mi], bf4[ni], acc[mi][ni], 0, 0, 0);
            __builtin_amdgcn_s_setprio(0);
            __builtin_amdgcn_s_barrier();
        }
    }

    const float qscale = 0.125f * 1.44269504f;

    if (MODE == 0) {
        const int z = (int)(colB0 >> 10);
        #pragma unroll
        for (int mi = 0; mi < 4; mi++) {
            #pragma unroll
            for (int ni = 0; ni < 4; ni++) {
                const long col = colB0 + wn + ni * 16 + l16;
                const long c   = col & 1023;
                const long row0 = rowA0 + wm + mi * 16 + quad * 4;
                if (z == 2) {
                    const long h_ = c >> 6, dd = c & 63;
                    const long b_ = row0 >> 11, s0 = row0 & 2047;
                    v4bf pk;
                    #pragma unroll
                    for (int r = 0; r < 4; r++) pk[r] = (bf16)acc[mi][ni][r];
                    *(v4bf*)(Ov + ((b_ * 16 + h_) * 64 + dd) * 2048 + s0) = pk;
                } else {
                    bf16* Ob = (z == 0) ? Oq : Ok;
                    #pragma unroll
                    for (int r = 0; r < 4; r++) {
                        float v = acc[mi][ni][r];
                        if (z == 0) v *= qscale;
                        Ob[(row0 + r) * D + c] = (bf16)v;
                    }
                }
            }
        }
    } else {
        #pragma unroll
        for (int mi = 0; mi < 4; mi++) {
            #pragma unroll
            for (int ni = 0; ni < 4; ni++) {
                const long col = colB0 + wn + ni * 16 + l16;
                const float bv = bias[col];
                #pragma unroll
                for (int r = 0; r < 4; r++) {
                    const long row = rowA0 + wm + mi * 16 + quad * 4 + r;
                    Of[row * D + col] = acc[mi][ni][r] + bv + X[row * D + col];
                }
            }
        }
    }
}

// ----------------------------------------------------------- attention ----
// 512 blocks (XCD-grouped decode), 512 threads = 8 waves x 32 q-rows
// (q-tile 256). 32x32x16 MFMA, swapped QK^T, in-register P transpose
// (cvt_pk + permlane32_swap). K/V staged by global_load_lds DMA into a
// 3-buffer ring (48 KiB): per k-tile {stage t+2; compute t; vmcnt(2);
// barrier} -- t+1's loads land while t+2's stay in flight (never drain
// to 0 mid-loop). XOR swizzle moved to the per-lane GLOBAL source
// address (LDS dest is wave-linear, as DMA requires); reads use
// chunk ^ (row&7) as before. No reg-staging VALU, no ds_writes.
__global__ __launch_bounds__(512, 2) void attn_kernel(
    const bf16* __restrict__ Q, const bf16* __restrict__ Kg,
    const bf16* __restrict__ VtG, bf16* __restrict__ O)
{
    const int id  = blockIdx.x;
    const int xcd = id & 7, j = id >> 3;
    const int qt  = j & 7;
    const int g   = xcd + 8 * (j >> 3);
    const int h   = g & 15, b = g >> 4;

    const int tid  = threadIdx.x;
    const int lane = tid & 63;
    const int wave = tid >> 6;
    const int l31  = lane & 31;
    const int hi   = lane >> 5;

    __shared__ bf16 Kt[3][64 * 64];   // K[kk][d], swizzled
    __shared__ bf16 Vt[3][64 * 64];   // V^T[d][kk], swizzled

    const long qrow = (long)(b * 2048 + qt * 256 + wave * 32 + l31);
    v8bf qB[4];
    #pragma unroll
    for (int f = 0; f < 4; f++)
        qB[f] = *(const v8bf*)(Q + qrow * D + h * 64 + f * 16 + hi * 8);

    const v16f z16 = {0.f,0.f,0.f,0.f,0.f,0.f,0.f,0.f,
                      0.f,0.f,0.f,0.f,0.f,0.f,0.f,0.f};
    v16f o_acc[2];
    o_acc[0] = z16; o_acc[1] = z16;
    float l0 = 0.f, l1 = 0.f;

    // staging: row iR (0..63), 16B chunk c8; source column pre-swizzled so
    // the wave-linear DMA fill produces LDS[row][chunk c^(row&7)] layout.
    const int iR  = tid >> 3;
    const int c8  = tid & 7;
    const int csw = ((c8 ^ (iR & 7)) * 8);
    const bf16* kSrc = Kg  + (long)b * 2048 * D + h * 64 + csw + (long)iR * D;
    const bf16* vSrc = VtG + (long)(b * 16 + h) * 64 * 2048 + csw + (long)iR * 2048;
    const int ldsOff = wave * 512;   // elems; wave-uniform base, lane*16B fill

    auto stage = [&](int bi, int t) {
        __builtin_amdgcn_global_load_lds(
            (const GAS void*)(kSrc + (long)t * 64 * D),
            (LAS void*)(&Kt[bi][ldsOff]), 16, 0, 0);
        __builtin_amdgcn_global_load_lds(
            (const GAS void*)(vSrc + t * 64),
            (LAS void*)(&Vt[bi][ldsOff]), 16, 0, 0);
    };

    auto compute = [&](const int bq) {
        #pragma unroll
        for (int ko = 0; ko < 2; ko++) {
            const int krow = ko * 32 + l31;
            const int ksw  = krow & 7;
            v8bf kA[4];
            #pragma unroll
            for (int f = 0; f < 4; f++)
                kA[f] = *(const v8bf*)(&Kt[bq][krow * 64 + (((2 * f + hi) ^ ksw) * 8)]);
            __builtin_amdgcn_s_setprio(1);
            v16f st = __builtin_amdgcn_mfma_f32_32x32x16_bf16(kA[0], qB[0], z16, 0, 0, 0);
            st = __builtin_amdgcn_mfma_f32_32x32x16_bf16(kA[1], qB[1], st, 0, 0, 0);
            st = __builtin_amdgcn_mfma_f32_32x32x16_bf16(kA[2], qB[2], st, 0, 0, 0);
            st = __builtin_amdgcn_mfma_f32_32x32x16_bf16(kA[3], qB[3], st, 0, 0, 0);
            __builtin_amdgcn_s_setprio(0);

            float p[16];
            #pragma unroll
            for (int r = 0; r < 16; r++) {
                p[r] = __builtin_amdgcn_exp2f(st[r]);
                if (r & 1) l1 += p[r]; else l0 += p[r];
            }

            #pragma unroll
            for (int u = 0; u < 2; u++) {
                const int s = ko * 2 + u;
                u32 a0, a1, b0, b1;
                asm("v_cvt_pk_bf16_f32 %0, %1, %2" : "=v"(a0) : "v"(p[u*8+0]), "v"(p[u*8+1]));
                asm("v_cvt_pk_bf16_f32 %0, %1, %2" : "=v"(a1) : "v"(p[u*8+2]), "v"(p[u*8+3]));
                asm("v_cvt_pk_bf16_f32 %0, %1, %2" : "=v"(b0) : "v"(p[u*8+4]), "v"(p[u*8+5]));
                asm("v_cvt_pk_bf16_f32 %0, %1, %2" : "=v"(b1) : "v"(p[u*8+6]), "v"(p[u*8+7]));
                asm("v_permlane32_swap_b32 %0, %1" : "+v"(a0), "+v"(b0));
                asm("v_permlane32_swap_b32 %0, %1" : "+v"(a1), "+v"(b1));
                v4u w; w[0] = a0; w[1] = a1; w[2] = b0; w[3] = b1;
                const v8bf pa = __builtin_bit_cast(v8bf, w);
                const int vsw = (l31 & 7);
                v8bf vb0 = *(const v8bf*)(&Vt[bq][(l31)      * 64 + (((2 * s + hi) ^ vsw) * 8)]);
                v8bf vb1 = *(const v8bf*)(&Vt[bq][(32 + l31) * 64 + (((2 * s + hi) ^ vsw) * 8)]);
                __builtin_amdgcn_s_setprio(1);
                o_acc[0] = __builtin_amdgcn_mfma_f32_32x32x16_bf16(pa, vb0, o_acc[0], 0, 0, 0);
                o_acc[1] = __builtin_amdgcn_mfma_f32_32x32x16_bf16(pa, vb1, o_acc[1], 0, 0, 0);
                __builtin_amdgcn_s_setprio(0);
            }
        }
    };

    stage(0, 0);
    stage(1, 1);
    asm volatile("s_waitcnt vmcnt(2)" ::: "memory");
    __builtin_amdgcn_s_barrier();

    for (int kt = 0; kt < 32; ++kt) {
        const int bi = kt % 3;
        if (kt + 2 < 32) stage((kt + 2) % 3, kt + 2);
        compute(bi);
        if (kt + 1 < 32) {
            if (kt + 2 < 32) asm volatile("s_waitcnt vmcnt(2)" ::: "memory");
            else             asm volatile("s_waitcnt vmcnt(0)" ::: "memory");
            __builtin_amdgcn_s_barrier();
        }
    }

    float l_acc = l0 + l1;
    l_acc += __shfl_xor(l_acc, 32);

    const long obase = (long)(b * 2048 + qt * 256 + wave * 32);
    #pragma unroll
    for (int r = 0; r < 16; r++) {
        const int qp = (r & 3) + 8 * (r >> 2) + 4 * hi;
        const float inv = 1.f / __shfl(l_acc, qp);
        O[(obase + qp) * D + h * 64 + l31]      = (bf16)(o_acc[0][r] * inv);
        O[(obase + qp) * D + h * 64 + 32 + l31] = (bf16)(o_acc[1][r] * inv);
    }
}

// ------------------------------------------------------------------ LN ----
__global__ __launch_bounds__(256) void ln_kernel(
    const float* __restrict__ g, const float* __restrict__ beta,
    float* __restrict__ out)
{
    const int row = blockIdx.x;
    const int t = threadIdx.x;
    const int lane = t & 63, wave = t >> 6;
    const long base = (long)row * D + t * 4;

    float4 yv = *(const float4*)(out + base);
    float y0 = yv.x, y1 = yv.y, y2 = yv.z, y3 = yv.w;
    float s1 = y0 + y1 + y2 + y3;
    float s2 = y0*y0 + y1*y1 + y2*y2 + y3*y3;
    #pragma unroll
    for (int off = 1; off < 64; off <<= 1) {
        s1 += __shfl_xor(s1, off);
        s2 += __shfl_xor(s2, off);
    }
    __shared__ float r1[4], r2[4];
    if (lane == 0) { r1[wave] = s1; r2[wave] = s2; }
    __syncthreads();
    float S1 = r1[0] + r1[1] + r1[2] + r1[3];
    float S2 = r2[0] + r2[1] + r2[2] + r2[3];
    float mu  = S1 * (1.f / 1024.f);
    float var = S2 * (1.f / 1024.f) - mu * mu;
    float rsd = rsqrtf(var + 1e-5f);

    float4 gv = *(const float4*)(g + t * 4);
    float4 bv = *(const float4*)(beta + t * 4);
    float4 o;
    o.x = (y0 - mu) * rsd * gv.x + bv.x;
    o.y = (y1 - mu) * rsd * gv.y + bv.y;
    o.z = (y2 - mu) * rsd * gv.z + bv.z;
    o.w = (y3 - mu) * rsd * gv.w + bv.w;
    *(float4*)(out + base) = o;
}

// ---------------------------------------------------------------- launch --
extern "C" void kernel_launch(void* const* d_in, const int* in_sizes, int n_in,
                              void* d_out, int out_size, void* d_ws, size_t ws_size,
                              hipStream_t stream)
{
    const float* x   = (const float*)d_in[0];
    const float* wq  = (const float*)d_in[1];
    const float* wk  = (const float*)d_in[2];
    const float* wv  = (const float*)d_in[3];
    const float* wo  = (const float*)d_in[4];
    const float* bo  = (const float*)d_in[5];
    const float* lng = (const float*)d_in[6];
    const float* lnb = (const float*)d_in[7];
    float* out = (float*)d_out;

    char* ws = (char*)d_ws;
    bf16* xb  = (bf16*)(ws);                            // 16 MiB
    bf16* wqb = (bf16*)(ws + (size_t)16 * 1024 * 1024); // 4 x 2 MiB (contig QKV,O)
    bf16* wkb = wqb + 1024 * 1024;
    bf16* wvb = wkb + 1024 * 1024;
    bf16* wob = wvb + 1024 * 1024;
    bf16* Qb  = (bf16*)(ws + (size_t)24 * 1024 * 1024); // 4 x 16 MiB
    bf16* Kb  = Qb + (size_t)ROWS * D;
    bf16* VtG = Kb + (size_t)ROWS * D;                  // V transposed [b][h][d][s]
    bf16* Ab  = VtG + (size_t)ROWS * D;                 // total 88 MiB

    cast_all<<<12288, 256, 0, stream>>>(x, wq, wk, wv, wo,
                                        xb, wqb, wkb, wvb, wob);

    // QKV: one dispatch, W = [3072][1024] (wq|wk|wv contiguous). 768 blocks
    // = exactly 3 rounds of 256 CUs at 1 block/CU.
    gemm8<0, 24><<<768, 512, 0, stream>>>(xb, wqb, Qb, Kb, VtG,
                                          nullptr, nullptr, nullptr);

    attn_kernel<<<dim3(512, 1, 1), 512, 0, stream>>>(Qb, Kb, VtG, Ab);

    // Output proj: 256 blocks = exactly 1 full round.
    gemm8<1, 8><<<256, 512, 0, stream>>>(Ab, wob, nullptr, nullptr, nullptr,
                                         out, bo, x);

    ln_kernel<<<8192, 256, 0, stream>>>(lng, lnb, out);
}